// Round 12
// baseline (400.751 us; speedup 1.0000x reference)
//
#include <hip/hip_runtime.h>
#include <hip/hip_bf16.h>

#define NN 100000
#define EE 1600000
#define HF 128
#define GG 256
#define CCLS 10

// two-phase CSR build
#define PSH 9                       // 512 targets per partition
#define PTGT (1 << PSH)
#define NPART ((NN + PTGT - 1) >> PSH)   // 196
#define SLAB 9728                   // >= mean 8192 + 16 sigma
#define ACH 4096                    // edges per binA block
#define PCH 32                      // nodes per pool block

typedef __attribute__((ext_vector_type(8))) short bf16x8;
typedef __attribute__((ext_vector_type(4))) float f32x4;

#define WT_PITCH 136   // shorts; 272 B row pitch -> 16B-aligned b128 reads, 2-way banks (free)

__device__ __forceinline__ float bflo(uint u) { return __uint_as_float(u << 16); }
__device__ __forceinline__ float bfhi(uint u) { return __uint_as_float(u & 0xffff0000u); }
__device__ __forceinline__ uint packbf(float a, float b) {
  __hip_bfloat16 x = __float2bfloat16(a), y = __float2bfloat16(b);
  return (uint)*(unsigned short*)&x | ((uint)*(unsigned short*)&y << 16);
}

// ---------------- utility: zero part_tail (ints) + pool/cntg (floats) in one launch ----------------
__global__ __launch_bounds__(256) void k_zero2(int* __restrict__ a, int na, float* __restrict__ b, int nb) {
  int i = blockIdx.x * 256 + threadIdx.x;
  if (i < na) a[i] = 0;
  i -= na;
  if (i >= 0 && i < nb) b[i] = 0.f;
}

// ---------------- CSR build ----------------
// phase A: LDS-binned partition append. Each partition slab receives sequential bursts
// -> cache lines assemble fully in L2 -> write bytes ~= payload (no write-amp).
__global__ __launch_bounds__(256) void k_binA(const int* __restrict__ ei, const float* __restrict__ ec,
                                              int* __restrict__ part_tail, int2* __restrict__ stage) {
  __shared__ int cnt[NPART];
  __shared__ int base[NPART];
  const int tid = threadIdx.x;
  const int e0 = blockIdx.x * ACH;
  const int eend = min(e0 + ACH, EE);
  for (int t = tid; t < NPART; t += 256) cnt[t] = 0;
  __syncthreads();
  // pass 1: histogram
  for (int e = e0 + tid; e < eend; e += 256) {
    int c = ei[EE + e];
    atomicAdd(&cnt[c >> PSH], 1);
  }
  __syncthreads();
  // reserve slab ranges
  for (int t = tid; t < NPART; t += 256) {
    base[t] = (cnt[t] > 0) ? atomicAdd(&part_tail[t], cnt[t]) : 0;
  }
  __syncthreads();
  for (int t = tid; t < NPART; t += 256) cnt[t] = 0;
  __syncthreads();
  // pass 2: append (r | tl<<17, ec)
  for (int e = e0 + tid; e < eend; e += 256) {
    int c = ei[EE + e];
    int r = ei[e];
    float w = ec[e];
    int p = c >> PSH, tl = c & (PTGT - 1);
    int rank = atomicAdd(&cnt[p], 1);
    stage[(size_t)p * SLAB + base[p] + rank] = make_int2(r | (tl << 17), __float_as_int(w));
  }
}

// exclusive scan of the 196 partition totals -> partition base offsets; also rowptr[NN]=EE
__global__ __launch_bounds__(256) void k_scanP(const int* __restrict__ part_tail, int* __restrict__ pbase,
                                               int* __restrict__ rowptr) {
  __shared__ int s[256];
  int tid = threadIdx.x;
  int orig = (tid < NPART) ? part_tail[tid] : 0;
  s[tid] = orig;
  __syncthreads();
  for (int off = 1; off < 256; off <<= 1) {
    int t = (tid >= off) ? s[tid - off] : 0;
    __syncthreads();
    s[tid] += t;
    __syncthreads();
  }
  if (tid < NPART) pbase[tid] = s[tid] - orig;
  if (tid == 255) rowptr[NN] = s[255];      // total == EE
}

// per-partition: LDS histogram (zero global atomics) -> local scan -> rowptr + dis/cself, coalesced
__global__ __launch_bounds__(256) void k_binCount(const int2* __restrict__ stage, const int* __restrict__ part_tail,
                                                  const int* __restrict__ pbase, const float* __restrict__ nc,
                                                  float* __restrict__ dis, float* __restrict__ cself,
                                                  int* __restrict__ rowptr) {
  __shared__ int lcnt[PTGT];
  __shared__ int wsum[4];
  const int p = blockIdx.x;
  const int tid = threadIdx.x;
  const int t0 = p << PSH;
  const int tmax = min(PTGT, NN - t0);
  for (int t = tid; t < PTGT; t += 256) lcnt[t] = 0;
  __syncthreads();
  const int n = part_tail[p];
  const int2* sl = stage + (size_t)p * SLAB;
  for (int j = tid; j < n; j += 256) {
    atomicAdd(&lcnt[((uint)sl[j].x) >> 17], 1);
  }
  __syncthreads();
  // pair-wise exclusive scan over 512 counters with 256 threads
  int c0 = lcnt[2 * tid], c1 = lcnt[2 * tid + 1];
  int val = c0 + c1;
  int lane = tid & 63, w = tid >> 6;
  int v = val;
  #pragma unroll
  for (int off = 1; off < 64; off <<= 1) {
    int t = __shfl_up(v, off, 64);
    if (lane >= off) v += t;
  }
  if (lane == 63) wsum[w] = v;
  __syncthreads();
  int woff = 0;
  for (int j = 0; j < w; ++j) woff += wsum[j];
  int ex = woff + v - val + pbase[p];       // exclusive offset of node t0+2*tid
  int t = 2 * tid;
  if (t < tmax) {
    rowptr[t0 + t] = ex;
    float d = (float)(c0 + 1);              // +1 self loop
    dis[t0 + t] = rsqrtf(d);
    cself[t0 + t] = nc[t0 + t] / d;
  }
  if (t + 1 < tmax) {
    rowptr[t0 + t + 1] = ex + c0;
    float d = (float)(c1 + 1);
    dis[t0 + t + 1] = rsqrtf(d);
    cself[t0 + t + 1] = nc[t0 + t + 1] / d;
  }
}

// phase B: exact CSR placement within one partition (csr writes confined to ~64KB L2 window)
__global__ __launch_bounds__(256) void k_binB(const int2* __restrict__ stage, const int* __restrict__ part_tail,
                                              const int* __restrict__ rowptr, const float* __restrict__ dis,
                                              int2* __restrict__ csr) {
  __shared__ int lcnt[PTGT];
  __shared__ float dsh[PTGT];
  const int p = blockIdx.x;
  const int tid = threadIdx.x;
  const int t0 = p << PSH;
  const int tmax = min(PTGT, NN - t0);
  for (int t = tid; t < tmax; t += 256) { lcnt[t] = 0; dsh[t] = dis[t0 + t]; }
  __syncthreads();
  const int n = part_tail[p];
  const int2* sl = stage + (size_t)p * SLAB;
  for (int j = tid; j < n; j += 256) {
    int2 en = sl[j];
    int tl = ((uint)en.x) >> 17;
    int r = en.x & 0x1FFFF;
    float coef = dis[r] * dsh[tl] * __int_as_float(en.y);
    int pos = rowptr[t0 + tl] + atomicAdd(&lcnt[tl], 1);
    csr[pos] = make_int2(r, __float_as_int(coef));
  }
}

// ---------------- MFMA GEMM: Hb[bf16x2-packed] = X @ W ----------------
// operand-swapped: D = (W^T)(X^T) so each lane holds 4 consecutive features of one node
template<int INF32>
__global__ __launch_bounds__(256) void k_gemm(const void* __restrict__ Xv, const float* __restrict__ W,
                                              uint* __restrict__ Hb) {
  __shared__ short Wt[128 * WT_PITCH];   // Wt[c][k] bf16, 34.8 KB
  const int tid = threadIdx.x;
  #pragma unroll
  for (int t = 0; t < 32; ++t) {
    int idx = t * 256 + tid;
    int c = idx & 127, kp = idx >> 7;      // kp 0..63
    float w0 = W[(2 * kp) * 128 + c];
    float w1 = W[(2 * kp + 1) * 128 + c];
    *(uint*)&Wt[c * WT_PITCH + 2 * kp] = packbf(w0, w1);
  }
  __syncthreads();

  const int wv = tid >> 6, lane = tid & 63;
  const int r15 = lane & 15, kgrp = lane >> 4;
  const int n0 = blockIdx.x * 128 + wv * 16 + r15;   // node tile 0
  const int n1 = n0 + 64;                            // node tile 1
  f32x4 acc[2][8] = {};

  #pragma unroll
  for (int kk = 0; kk < 4; ++kk) {
    const int kbase = kk * 32 + kgrp * 8;
    bf16x8 xf[2];
    #pragma unroll
    for (int t = 0; t < 2; ++t) {
      int n = t ? n1 : n0;
      if (n < NN) {
        if constexpr (INF32) {
          const float* xrow = (const float*)Xv + (size_t)n * 128 + kbase;
          float4 xa = *(const float4*)xrow;
          float4 xb = *(const float4*)(xrow + 4);
          uint4 pk;
          pk.x = packbf(xa.x, xa.y); pk.y = packbf(xa.z, xa.w);
          pk.z = packbf(xb.x, xb.y); pk.w = packbf(xb.z, xb.w);
          xf[t] = *(bf16x8*)&pk;
        } else {
          xf[t] = *(const bf16x8*)((const short*)Xv + (size_t)n * 128 + kbase);
        }
      } else {
        #pragma unroll
        for (int j = 0; j < 8; ++j) xf[t][j] = 0;
      }
    }
    #pragma unroll
    for (int cb = 0; cb < 8; ++cb) {
      bf16x8 wf = *(const bf16x8*)&Wt[(cb * 16 + r15) * WT_PITCH + kbase];
      acc[0][cb] = __builtin_amdgcn_mfma_f32_16x16x32_bf16(wf, xf[0], acc[0][cb], 0, 0, 0);
      acc[1][cb] = __builtin_amdgcn_mfma_f32_16x16x32_bf16(wf, xf[1], acc[1][cb], 0, 0, 0);
    }
  }

  // D: col(lane&15) = node, row = kgrp*4 + reg = feature-within-16-block
  #pragma unroll
  for (int t = 0; t < 2; ++t) {
    int n = t ? n1 : n0;
    if (n < NN) {
      #pragma unroll
      for (int cb = 0; cb < 8; ++cb) {
        uint2 o;
        o.x = packbf(acc[t][cb][0], acc[t][cb][1]);
        o.y = packbf(acc[t][cb][2], acc[t][cb][3]);
        *(uint2*)&Hb[(size_t)n * 64 + cb * 8 + kgrp * 2] = o;
      }
    }
  }
}

// ---------------- aggregation: AGGB[i] = relu(b + cself[i]*H[i] + sum_e c_e*H[src_e]) ----------------
// 2 waves per node: each wave gathers half the edge list (full 256B row per instruction),
// LDS combine; tiered 8/4/1 unroll keeps <=3 serial remainder gathers per wave.
__global__ __launch_bounds__(128) void k_aggregate(const uint* __restrict__ Hu,
                                                   const int2* __restrict__ csr,
                                                   const int* __restrict__ rowptr,
                                                   const float* __restrict__ cself,
                                                   const float* __restrict__ bias,
                                                   uint* __restrict__ AGGB) {
  __shared__ float sm[128];
  const int lane = threadIdx.x & 63;
  const int w = threadIdx.x >> 6;
  const int i = blockIdx.x;
  float acc0, acc1;                  // features 2*lane, 2*lane+1
  if (w == 0) {
    float2 bb = *(const float2*)&bias[lane * 2];
    uint u = Hu[(size_t)i * 64 + lane];
    float cs = cself[i];
    acc0 = bb.x + cs * bflo(u);
    acc1 = bb.y + cs * bfhi(u);
  } else {
    acc0 = acc1 = 0.f;
  }
  const int k0 = rowptr[i], ke = rowptr[i + 1];
  const int mid = k0 + ((ke - k0 + 1) >> 1);
  int k = w ? mid : k0;
  const int kend = w ? ke : mid;
  for (; k + 7 < kend; k += 8) {
    int2 e0 = csr[k],     e1 = csr[k + 1], e2 = csr[k + 2], e3 = csr[k + 3];
    int2 e4 = csr[k + 4], e5 = csr[k + 5], e6 = csr[k + 6], e7 = csr[k + 7];
    uint u0 = Hu[(size_t)e0.x * 64 + lane];
    uint u1 = Hu[(size_t)e1.x * 64 + lane];
    uint u2 = Hu[(size_t)e2.x * 64 + lane];
    uint u3 = Hu[(size_t)e3.x * 64 + lane];
    uint u4 = Hu[(size_t)e4.x * 64 + lane];
    uint u5 = Hu[(size_t)e5.x * 64 + lane];
    uint u6 = Hu[(size_t)e6.x * 64 + lane];
    uint u7 = Hu[(size_t)e7.x * 64 + lane];
    float c0 = __int_as_float(e0.y), c1 = __int_as_float(e1.y);
    float c2 = __int_as_float(e2.y), c3 = __int_as_float(e3.y);
    float c4 = __int_as_float(e4.y), c5 = __int_as_float(e5.y);
    float c6 = __int_as_float(e6.y), c7 = __int_as_float(e7.y);
    acc0 += c0 * bflo(u0); acc1 += c0 * bfhi(u0);
    acc0 += c1 * bflo(u1); acc1 += c1 * bfhi(u1);
    acc0 += c2 * bflo(u2); acc1 += c2 * bfhi(u2);
    acc0 += c3 * bflo(u3); acc1 += c3 * bfhi(u3);
    acc0 += c4 * bflo(u4); acc1 += c4 * bfhi(u4);
    acc0 += c5 * bflo(u5); acc1 += c5 * bfhi(u5);
    acc0 += c6 * bflo(u6); acc1 += c6 * bfhi(u6);
    acc0 += c7 * bflo(u7); acc1 += c7 * bfhi(u7);
  }
  if (k + 3 < kend) {
    int2 e0 = csr[k], e1 = csr[k + 1], e2 = csr[k + 2], e3 = csr[k + 3];
    uint u0 = Hu[(size_t)e0.x * 64 + lane];
    uint u1 = Hu[(size_t)e1.x * 64 + lane];
    uint u2 = Hu[(size_t)e2.x * 64 + lane];
    uint u3 = Hu[(size_t)e3.x * 64 + lane];
    float c0 = __int_as_float(e0.y), c1 = __int_as_float(e1.y);
    float c2 = __int_as_float(e2.y), c3 = __int_as_float(e3.y);
    acc0 += c0 * bflo(u0); acc1 += c0 * bfhi(u0);
    acc0 += c1 * bflo(u1); acc1 += c1 * bfhi(u1);
    acc0 += c2 * bflo(u2); acc1 += c2 * bfhi(u2);
    acc0 += c3 * bflo(u3); acc1 += c3 * bfhi(u3);
    k += 4;
  }
  for (; k < kend; ++k) {
    int2 e0 = csr[k];
    float c0 = __int_as_float(e0.y);
    uint u0 = Hu[(size_t)e0.x * 64 + lane];
    acc0 += c0 * bflo(u0); acc1 += c0 * bfhi(u0);
  }
  if (w == 1) { sm[lane] = acc0; sm[64 + lane] = acc1; }
  __syncthreads();
  if (w == 0) {
    acc0 += sm[lane];
    acc1 += sm[64 + lane];
    AGGB[(size_t)i * 64 + lane] = packbf(fmaxf(acc0, 0.f), fmaxf(acc1, 0.f));
  }
}

// ---------------- pooling: 32 nodes/block, 8-deep batched loads, run-aggregated atomics ----------------
__global__ __launch_bounds__(64) void k_pool(const uint* __restrict__ Hb, const int* __restrict__ batch,
                                             float* __restrict__ pool, float* __restrict__ cntg) {
  const int f = threadIdx.x;   // 0..63, features 2f, 2f+1
  const int n0 = blockIdx.x * PCH;
  const int nh = min(PCH, NN - n0);
  int g = batch[n0];
  float a0 = 0.f, a1 = 0.f;
  int run = 0;
  for (int base = 0; base < nh; base += 8) {
    const int m = min(8, nh - base);
    uint u[8];
    #pragma unroll
    for (int j = 0; j < 8; ++j)
      if (j < m) u[j] = Hb[(size_t)(n0 + base + j) * 64 + f];   // 8 independent gathers in flight
    #pragma unroll
    for (int j = 0; j < 8; ++j) {
      if (j < m) {
        int gn = batch[n0 + base + j];     // wave-uniform, L1-cached
        if (gn != g) {
          atomicAdd(&pool[(size_t)g * 128 + 2 * f], a0);
          atomicAdd(&pool[(size_t)g * 128 + 2 * f + 1], a1);
          if (f == 0) atomicAdd(&cntg[g], (float)run);
          a0 = a1 = 0.f; run = 0; g = gn;
        }
        a0 += bflo(u[j]); a1 += bfhi(u[j]);
        run++;
      }
    }
  }
  atomicAdd(&pool[(size_t)g * 128 + 2 * f], a0);
  atomicAdd(&pool[(size_t)g * 128 + 2 * f + 1], a1);
  if (f == 0) atomicAdd(&cntg[g], (float)run);
}

// ---------------- head ----------------
__global__ __launch_bounds__(64) void k_head(const float* __restrict__ pool, const float* __restrict__ cntg,
                                             const float* __restrict__ Wc, const float* __restrict__ bc,
                                             float* __restrict__ out) {
  int g = blockIdx.x;
  int lane = threadIdx.x;
  float inv = 1.f / fmaxf(cntg[g], 1.f);
  float p0 = pool[(size_t)g * 128 + lane] * inv;
  float p1 = pool[(size_t)g * 128 + 64 + lane] * inv;
  #pragma unroll
  for (int c = 0; c < CCLS; ++c) {
    float s = p0 * Wc[lane * CCLS + c] + p1 * Wc[(lane + 64) * CCLS + c];
    s += __shfl_down(s, 32, 64);
    s += __shfl_down(s, 16, 64);
    s += __shfl_down(s, 8, 64);
    s += __shfl_down(s, 4, 64);
    s += __shfl_down(s, 2, 64);
    s += __shfl_down(s, 1, 64);
    if (lane == 0) out[g * CCLS + c] = s + bc[c];
  }
}

extern "C" void kernel_launch(void* const* d_in, const int* in_sizes, int n_in,
                              void* d_out, int out_size, void* d_ws, size_t ws_size,
                              hipStream_t stream) {
  const float* x  = (const float*)d_in[0];
  const int* ei   = (const int*)d_in[1];
  const int* batch = (const int*)d_in[2];
  const float* nc = (const float*)d_in[3];
  const float* ec = (const float*)d_in[4];
  const float* W1 = (const float*)d_in[5];
  const float* b1 = (const float*)d_in[6];
  const float* W2 = (const float*)d_in[7];
  const float* b2 = (const float*)d_in[8];
  const float* W3 = (const float*)d_in[9];
  const float* b3 = (const float*)d_in[10];
  const float* Wc = (const float*)d_in[11];
  const float* bc = (const float*)d_in[12];
  float* out = (float*)d_out;

  char* ws = (char*)d_ws;
  const size_t BH = (size_t)NN * 64 * 4;         // 25.6 MB packed bf16x2
  uint* hbuf = (uint*)(ws);
  uint* aggb = (uint*)(ws + BH);
  int2* csr  = (int2*)(ws + 2 * BH);
  int2* stage = (int2*)(ws + 2 * BH + (size_t)EE * 8);
  char* p = ws + 2 * BH + (size_t)EE * 8 + (size_t)NPART * SLAB * 8;
  int*   part_tail= (int*)(p);                p += 1024;           // NPART=196 ints (padded)
  int*   pbase    = (int*)(p);                p += 1024;
  float* dis      = (float*)(p);              p += (size_t)NN * 4;
  float* cself    = (float*)(p);              p += (size_t)NN * 4;
  int*   rowptr   = (int*)(p);                p += ((size_t)NN + 32) * 4;
  float* pool     = (float*)(p);              p += (size_t)GG * 128 * 4;
  float* cntg     = (float*)(p);              p += (size_t)GG * 4;

  const int ZN2 = GG * 128 + GG;          // pool + cntg
  const int nbinA = (EE + ACH - 1) / ACH; // 391

  // CSR build: zero -> binA (stage by partition) -> scanP -> binCount (hist+scan -> rowptr/dis/cself)
  //            -> binB (exact placement)
  k_zero2<<<(256 + ZN2 + 255) / 256, 256, 0, stream>>>(part_tail, 256, pool, ZN2);
  k_binA<<<nbinA, 256, 0, stream>>>(ei, ec, part_tail, stage);
  k_scanP<<<1, 256, 0, stream>>>(part_tail, pbase, rowptr);
  k_binCount<<<NPART, 256, 0, stream>>>(stage, part_tail, pbase, nc, dis, cself, rowptr);
  k_binB<<<NPART, 256, 0, stream>>>(stage, part_tail, rowptr, dis, csr);

  // 3 GCN layers: mfma-gemm -> aggregate (relu'd bf16 out)
  const float* Ws[3] = {W1, W2, W3};
  const float* bs[3] = {b1, b2, b3};
  const int gemm_grid = (NN + 127) / 128;
  for (int l = 0; l < 3; ++l) {
    if (l == 0) k_gemm<1><<<gemm_grid, 256, 0, stream>>>((const void*)x, Ws[l], hbuf);
    else        k_gemm<0><<<gemm_grid, 256, 0, stream>>>((const void*)aggb, Ws[l], hbuf);
    k_aggregate<<<NN, 128, 0, stream>>>(hbuf, csr, rowptr, cself, bs[l], aggb);
  }

  // pooling + head
  k_pool<<<(NN + PCH - 1) / PCH, 64, 0, stream>>>(aggb, batch, pool, cntg);
  k_head<<<GG, 64, 0, stream>>>(pool, cntg, Wc, bc, out);
}

// Round 13
// 325.103 us; speedup vs baseline: 1.2327x; 1.2327x over previous
//
#include <hip/hip_runtime.h>
#include <hip/hip_bf16.h>

#define NN 100000
#define EE 1600000
#define HF 128
#define GG 256
#define CCLS 10

// two-phase CSR build
#define PSH 9                       // 512 targets per partition
#define PTGT (1 << PSH)
#define NPART ((NN + PTGT - 1) >> PSH)   // 196
#define SLAB 9728                   // >= mean 8192 + 16 sigma
#define ACH 4096                    // edges per binA block
#define PCH 32                      // nodes per pool block

typedef __attribute__((ext_vector_type(8))) short bf16x8;
typedef __attribute__((ext_vector_type(4))) float f32x4;

#define WT_PITCH 136   // shorts; 272 B row pitch -> 16B-aligned b128 reads, 2-way banks (free)

__device__ __forceinline__ float bflo(uint u) { return __uint_as_float(u << 16); }
__device__ __forceinline__ float bfhi(uint u) { return __uint_as_float(u & 0xffff0000u); }
__device__ __forceinline__ uint packbf(float a, float b) {
  __hip_bfloat16 x = __float2bfloat16(a), y = __float2bfloat16(b);
  return (uint)*(unsigned short*)&x | ((uint)*(unsigned short*)&y << 16);
}

// ---------------- utility: zero part_tail (ints) + pool/cntg (floats) in one launch ----------------
__global__ __launch_bounds__(256) void k_zero2(int* __restrict__ a, int na, float* __restrict__ b, int nb) {
  int i = blockIdx.x * 256 + threadIdx.x;
  if (i < na) a[i] = 0;
  i -= na;
  if (i >= 0 && i < nb) b[i] = 0.f;
}

// ---------------- CSR build ----------------
// phase A: LDS-binned partition append. Each partition slab receives sequential bursts
// -> cache lines assemble fully in L2 -> write bytes ~= payload (no write-amp).
__global__ __launch_bounds__(256) void k_binA(const int* __restrict__ ei, const float* __restrict__ ec,
                                              int* __restrict__ part_tail, int2* __restrict__ stage) {
  __shared__ int cnt[NPART];
  __shared__ int base[NPART];
  const int tid = threadIdx.x;
  const int e0 = blockIdx.x * ACH;
  const int eend = min(e0 + ACH, EE);
  for (int t = tid; t < NPART; t += 256) cnt[t] = 0;
  __syncthreads();
  // pass 1: histogram
  for (int e = e0 + tid; e < eend; e += 256) {
    int c = ei[EE + e];
    atomicAdd(&cnt[c >> PSH], 1);
  }
  __syncthreads();
  // reserve slab ranges
  for (int t = tid; t < NPART; t += 256) {
    base[t] = (cnt[t] > 0) ? atomicAdd(&part_tail[t], cnt[t]) : 0;
  }
  __syncthreads();
  for (int t = tid; t < NPART; t += 256) cnt[t] = 0;
  __syncthreads();
  // pass 2: append (r | tl<<17, ec)
  for (int e = e0 + tid; e < eend; e += 256) {
    int c = ei[EE + e];
    int r = ei[e];
    float w = ec[e];
    int p = c >> PSH, tl = c & (PTGT - 1);
    int rank = atomicAdd(&cnt[p], 1);
    stage[(size_t)p * SLAB + base[p] + rank] = make_int2(r | (tl << 17), __float_as_int(w));
  }
}

// exclusive scan of the 196 partition totals -> partition base offsets; also rowptr[NN]=EE
__global__ __launch_bounds__(256) void k_scanP(const int* __restrict__ part_tail, int* __restrict__ pbase,
                                               int* __restrict__ rowptr) {
  __shared__ int s[256];
  int tid = threadIdx.x;
  int orig = (tid < NPART) ? part_tail[tid] : 0;
  s[tid] = orig;
  __syncthreads();
  for (int off = 1; off < 256; off <<= 1) {
    int t = (tid >= off) ? s[tid - off] : 0;
    __syncthreads();
    s[tid] += t;
    __syncthreads();
  }
  if (tid < NPART) pbase[tid] = s[tid] - orig;
  if (tid == 255) rowptr[NN] = s[255];      // total == EE
}

// per-partition: LDS histogram (zero global atomics) -> local scan -> rowptr + dis/cself, coalesced
__global__ __launch_bounds__(256) void k_binCount(const int2* __restrict__ stage, const int* __restrict__ part_tail,
                                                  const int* __restrict__ pbase, const float* __restrict__ nc,
                                                  float* __restrict__ dis, float* __restrict__ cself,
                                                  int* __restrict__ rowptr) {
  __shared__ int lcnt[PTGT];
  __shared__ int wsum[4];
  const int p = blockIdx.x;
  const int tid = threadIdx.x;
  const int t0 = p << PSH;
  const int tmax = min(PTGT, NN - t0);
  for (int t = tid; t < PTGT; t += 256) lcnt[t] = 0;
  __syncthreads();
  const int n = part_tail[p];
  const int2* sl = stage + (size_t)p * SLAB;
  for (int j = tid; j < n; j += 256) {
    atomicAdd(&lcnt[((uint)sl[j].x) >> 17], 1);
  }
  __syncthreads();
  // pair-wise exclusive scan over 512 counters with 256 threads
  int c0 = lcnt[2 * tid], c1 = lcnt[2 * tid + 1];
  int val = c0 + c1;
  int lane = tid & 63, w = tid >> 6;
  int v = val;
  #pragma unroll
  for (int off = 1; off < 64; off <<= 1) {
    int t = __shfl_up(v, off, 64);
    if (lane >= off) v += t;
  }
  if (lane == 63) wsum[w] = v;
  __syncthreads();
  int woff = 0;
  for (int j = 0; j < w; ++j) woff += wsum[j];
  int ex = woff + v - val + pbase[p];       // exclusive offset of node t0+2*tid
  int t = 2 * tid;
  if (t < tmax) {
    rowptr[t0 + t] = ex;
    float d = (float)(c0 + 1);              // +1 self loop
    dis[t0 + t] = rsqrtf(d);
    cself[t0 + t] = nc[t0 + t] / d;
  }
  if (t + 1 < tmax) {
    rowptr[t0 + t + 1] = ex + c0;
    float d = (float)(c1 + 1);
    dis[t0 + t + 1] = rsqrtf(d);
    cself[t0 + t + 1] = nc[t0 + t + 1] / d;
  }
}

// phase B: exact CSR placement within one partition (csr writes confined to ~64KB L2 window)
__global__ __launch_bounds__(256) void k_binB(const int2* __restrict__ stage, const int* __restrict__ part_tail,
                                              const int* __restrict__ rowptr, const float* __restrict__ dis,
                                              int2* __restrict__ csr) {
  __shared__ int lcnt[PTGT];
  __shared__ float dsh[PTGT];
  const int p = blockIdx.x;
  const int tid = threadIdx.x;
  const int t0 = p << PSH;
  const int tmax = min(PTGT, NN - t0);
  for (int t = tid; t < tmax; t += 256) { lcnt[t] = 0; dsh[t] = dis[t0 + t]; }
  __syncthreads();
  const int n = part_tail[p];
  const int2* sl = stage + (size_t)p * SLAB;
  for (int j = tid; j < n; j += 256) {
    int2 en = sl[j];
    int tl = ((uint)en.x) >> 17;
    int r = en.x & 0x1FFFF;
    float coef = dis[r] * dsh[tl] * __int_as_float(en.y);
    int pos = rowptr[t0 + tl] + atomicAdd(&lcnt[tl], 1);
    csr[pos] = make_int2(r, __float_as_int(coef));
  }
}

// ---------------- MFMA GEMM: Hb[bf16x2-packed] = X @ W ----------------
// operand-swapped: D = (W^T)(X^T) so each lane holds 4 consecutive features of one node
template<int INF32>
__global__ __launch_bounds__(256) void k_gemm(const void* __restrict__ Xv, const float* __restrict__ W,
                                              uint* __restrict__ Hb) {
  __shared__ short Wt[128 * WT_PITCH];   // Wt[c][k] bf16, 34.8 KB
  const int tid = threadIdx.x;
  #pragma unroll
  for (int t = 0; t < 32; ++t) {
    int idx = t * 256 + tid;
    int c = idx & 127, kp = idx >> 7;      // kp 0..63
    float w0 = W[(2 * kp) * 128 + c];
    float w1 = W[(2 * kp + 1) * 128 + c];
    *(uint*)&Wt[c * WT_PITCH + 2 * kp] = packbf(w0, w1);
  }
  __syncthreads();

  const int wv = tid >> 6, lane = tid & 63;
  const int r15 = lane & 15, kgrp = lane >> 4;
  const int n0 = blockIdx.x * 128 + wv * 16 + r15;   // node tile 0
  const int n1 = n0 + 64;                            // node tile 1
  f32x4 acc[2][8] = {};

  #pragma unroll
  for (int kk = 0; kk < 4; ++kk) {
    const int kbase = kk * 32 + kgrp * 8;
    bf16x8 xf[2];
    #pragma unroll
    for (int t = 0; t < 2; ++t) {
      int n = t ? n1 : n0;
      if (n < NN) {
        if constexpr (INF32) {
          const float* xrow = (const float*)Xv + (size_t)n * 128 + kbase;
          float4 xa = *(const float4*)xrow;
          float4 xb = *(const float4*)(xrow + 4);
          uint4 pk;
          pk.x = packbf(xa.x, xa.y); pk.y = packbf(xa.z, xa.w);
          pk.z = packbf(xb.x, xb.y); pk.w = packbf(xb.z, xb.w);
          xf[t] = *(bf16x8*)&pk;
        } else {
          xf[t] = *(const bf16x8*)((const short*)Xv + (size_t)n * 128 + kbase);
        }
      } else {
        #pragma unroll
        for (int j = 0; j < 8; ++j) xf[t][j] = 0;
      }
    }
    #pragma unroll
    for (int cb = 0; cb < 8; ++cb) {
      bf16x8 wf = *(const bf16x8*)&Wt[(cb * 16 + r15) * WT_PITCH + kbase];
      acc[0][cb] = __builtin_amdgcn_mfma_f32_16x16x32_bf16(wf, xf[0], acc[0][cb], 0, 0, 0);
      acc[1][cb] = __builtin_amdgcn_mfma_f32_16x16x32_bf16(wf, xf[1], acc[1][cb], 0, 0, 0);
    }
  }

  // D: col(lane&15) = node, row = kgrp*4 + reg = feature-within-16-block
  #pragma unroll
  for (int t = 0; t < 2; ++t) {
    int n = t ? n1 : n0;
    if (n < NN) {
      #pragma unroll
      for (int cb = 0; cb < 8; ++cb) {
        uint2 o;
        o.x = packbf(acc[t][cb][0], acc[t][cb][1]);
        o.y = packbf(acc[t][cb][2], acc[t][cb][3]);
        *(uint2*)&Hb[(size_t)n * 64 + cb * 8 + kgrp * 2] = o;
      }
    }
  }
}

// ---------------- aggregation: AGGB[i] = relu(b + cself[i]*H[i] + sum_e c_e*H[src_e]) ----------------
// 1 node per 64-thread block, uniform CSR reads, 8x unroll for 8 in-flight gathers
// (round-11 version, measured 61us/layer; 2-wave split regressed to 88us -- keep 1 wave/node)
__global__ __launch_bounds__(64) void k_aggregate(const uint* __restrict__ Hu,
                                                  const int2* __restrict__ csr,
                                                  const int* __restrict__ rowptr,
                                                  const float* __restrict__ cself,
                                                  const float* __restrict__ bias,
                                                  uint* __restrict__ AGGB) {
  const int lane = threadIdx.x;
  const int i = blockIdx.x;
  float2 bb = *(const float2*)&bias[lane * 2];
  float acc0 = bb.x, acc1 = bb.y;     // features 2*lane, 2*lane+1
  float cs = cself[i];
  {
    uint u = Hu[(size_t)i * 64 + lane];
    acc0 += cs * bflo(u);
    acc1 += cs * bfhi(u);
  }
  int k = rowptr[i], ke = rowptr[i + 1];
  for (; k + 7 < ke; k += 8) {
    int2 e0 = csr[k],     e1 = csr[k + 1], e2 = csr[k + 2], e3 = csr[k + 3];
    int2 e4 = csr[k + 4], e5 = csr[k + 5], e6 = csr[k + 6], e7 = csr[k + 7];
    uint u0 = Hu[(size_t)e0.x * 64 + lane];
    uint u1 = Hu[(size_t)e1.x * 64 + lane];
    uint u2 = Hu[(size_t)e2.x * 64 + lane];
    uint u3 = Hu[(size_t)e3.x * 64 + lane];
    uint u4 = Hu[(size_t)e4.x * 64 + lane];
    uint u5 = Hu[(size_t)e5.x * 64 + lane];
    uint u6 = Hu[(size_t)e6.x * 64 + lane];
    uint u7 = Hu[(size_t)e7.x * 64 + lane];
    float c0 = __int_as_float(e0.y), c1 = __int_as_float(e1.y);
    float c2 = __int_as_float(e2.y), c3 = __int_as_float(e3.y);
    float c4 = __int_as_float(e4.y), c5 = __int_as_float(e5.y);
    float c6 = __int_as_float(e6.y), c7 = __int_as_float(e7.y);
    acc0 += c0 * bflo(u0); acc1 += c0 * bfhi(u0);
    acc0 += c1 * bflo(u1); acc1 += c1 * bfhi(u1);
    acc0 += c2 * bflo(u2); acc1 += c2 * bfhi(u2);
    acc0 += c3 * bflo(u3); acc1 += c3 * bfhi(u3);
    acc0 += c4 * bflo(u4); acc1 += c4 * bfhi(u4);
    acc0 += c5 * bflo(u5); acc1 += c5 * bfhi(u5);
    acc0 += c6 * bflo(u6); acc1 += c6 * bfhi(u6);
    acc0 += c7 * bflo(u7); acc1 += c7 * bfhi(u7);
  }
  for (; k < ke; ++k) {
    int2 e0 = csr[k];
    float c0 = __int_as_float(e0.y);
    uint u0 = Hu[(size_t)e0.x * 64 + lane];
    acc0 += c0 * bflo(u0); acc1 += c0 * bfhi(u0);
  }
  AGGB[(size_t)i * 64 + lane] = packbf(fmaxf(acc0, 0.f), fmaxf(acc1, 0.f));
}

// ---------------- pooling: 32 nodes/block, 8-deep batched loads, run-aggregated atomics ----------------
__global__ __launch_bounds__(64) void k_pool(const uint* __restrict__ Hb, const int* __restrict__ batch,
                                             float* __restrict__ pool, float* __restrict__ cntg) {
  const int f = threadIdx.x;   // 0..63, features 2f, 2f+1
  const int n0 = blockIdx.x * PCH;
  const int nh = min(PCH, NN - n0);
  int g = batch[n0];
  float a0 = 0.f, a1 = 0.f;
  int run = 0;
  for (int base = 0; base < nh; base += 8) {
    const int m = min(8, nh - base);
    uint u[8];
    #pragma unroll
    for (int j = 0; j < 8; ++j)
      if (j < m) u[j] = Hb[(size_t)(n0 + base + j) * 64 + f];   // 8 independent gathers in flight
    #pragma unroll
    for (int j = 0; j < 8; ++j) {
      if (j < m) {
        int gn = batch[n0 + base + j];     // wave-uniform, L1-cached
        if (gn != g) {
          atomicAdd(&pool[(size_t)g * 128 + 2 * f], a0);
          atomicAdd(&pool[(size_t)g * 128 + 2 * f + 1], a1);
          if (f == 0) atomicAdd(&cntg[g], (float)run);
          a0 = a1 = 0.f; run = 0; g = gn;
        }
        a0 += bflo(u[j]); a1 += bfhi(u[j]);
        run++;
      }
    }
  }
  atomicAdd(&pool[(size_t)g * 128 + 2 * f], a0);
  atomicAdd(&pool[(size_t)g * 128 + 2 * f + 1], a1);
  if (f == 0) atomicAdd(&cntg[g], (float)run);
}

// ---------------- head ----------------
__global__ __launch_bounds__(64) void k_head(const float* __restrict__ pool, const float* __restrict__ cntg,
                                             const float* __restrict__ Wc, const float* __restrict__ bc,
                                             float* __restrict__ out) {
  int g = blockIdx.x;
  int lane = threadIdx.x;
  float inv = 1.f / fmaxf(cntg[g], 1.f);
  float p0 = pool[(size_t)g * 128 + lane] * inv;
  float p1 = pool[(size_t)g * 128 + 64 + lane] * inv;
  #pragma unroll
  for (int c = 0; c < CCLS; ++c) {
    float s = p0 * Wc[lane * CCLS + c] + p1 * Wc[(lane + 64) * CCLS + c];
    s += __shfl_down(s, 32, 64);
    s += __shfl_down(s, 16, 64);
    s += __shfl_down(s, 8, 64);
    s += __shfl_down(s, 4, 64);
    s += __shfl_down(s, 2, 64);
    s += __shfl_down(s, 1, 64);
    if (lane == 0) out[g * CCLS + c] = s + bc[c];
  }
}

extern "C" void kernel_launch(void* const* d_in, const int* in_sizes, int n_in,
                              void* d_out, int out_size, void* d_ws, size_t ws_size,
                              hipStream_t stream) {
  const float* x  = (const float*)d_in[0];
  const int* ei   = (const int*)d_in[1];
  const int* batch = (const int*)d_in[2];
  const float* nc = (const float*)d_in[3];
  const float* ec = (const float*)d_in[4];
  const float* W1 = (const float*)d_in[5];
  const float* b1 = (const float*)d_in[6];
  const float* W2 = (const float*)d_in[7];
  const float* b2 = (const float*)d_in[8];
  const float* W3 = (const float*)d_in[9];
  const float* b3 = (const float*)d_in[10];
  const float* Wc = (const float*)d_in[11];
  const float* bc = (const float*)d_in[12];
  float* out = (float*)d_out;

  char* ws = (char*)d_ws;
  const size_t BH = (size_t)NN * 64 * 4;         // 25.6 MB packed bf16x2
  uint* hbuf = (uint*)(ws);
  uint* aggb = (uint*)(ws + BH);
  int2* csr  = (int2*)(ws + 2 * BH);
  int2* stage = (int2*)(ws + 2 * BH + (size_t)EE * 8);
  char* p = ws + 2 * BH + (size_t)EE * 8 + (size_t)NPART * SLAB * 8;
  int*   part_tail= (int*)(p);                p += 1024;           // NPART=196 ints (padded)
  int*   pbase    = (int*)(p);                p += 1024;
  float* dis      = (float*)(p);              p += (size_t)NN * 4;
  float* cself    = (float*)(p);              p += (size_t)NN * 4;
  int*   rowptr   = (int*)(p);                p += ((size_t)NN + 32) * 4;
  float* pool     = (float*)(p);              p += (size_t)GG * 128 * 4;
  float* cntg     = (float*)(p);              p += (size_t)GG * 4;

  const int ZN2 = GG * 128 + GG;          // pool + cntg
  const int nbinA = (EE + ACH - 1) / ACH; // 391

  // CSR build: zero -> binA (stage by partition) -> scanP -> binCount (hist+scan -> rowptr/dis/cself)
  //            -> binB (exact placement)
  k_zero2<<<(256 + ZN2 + 255) / 256, 256, 0, stream>>>(part_tail, 256, pool, ZN2);
  k_binA<<<nbinA, 256, 0, stream>>>(ei, ec, part_tail, stage);
  k_scanP<<<1, 256, 0, stream>>>(part_tail, pbase, rowptr);
  k_binCount<<<NPART, 256, 0, stream>>>(stage, part_tail, pbase, nc, dis, cself, rowptr);
  k_binB<<<NPART, 256, 0, stream>>>(stage, part_tail, rowptr, dis, csr);

  // 3 GCN layers: mfma-gemm -> aggregate (relu'd bf16 out)
  const float* Ws[3] = {W1, W2, W3};
  const float* bs[3] = {b1, b2, b3};
  const int gemm_grid = (NN + 127) / 128;
  for (int l = 0; l < 3; ++l) {
    if (l == 0) k_gemm<1><<<gemm_grid, 256, 0, stream>>>((const void*)x, Ws[l], hbuf);
    else        k_gemm<0><<<gemm_grid, 256, 0, stream>>>((const void*)aggb, Ws[l], hbuf);
    k_aggregate<<<NN, 64, 0, stream>>>(hbuf, csr, rowptr, cself, bs[l], aggb);
  }

  // pooling + head
  k_pool<<<(NN + PCH - 1) / PCH, 64, 0, stream>>>(aggb, batch, pool, cntg);
  k_head<<<GG, 64, 0, stream>>>(pool, cntg, Wc, bc, out);
}